// Round 1
// baseline (175.140 us; speedup 1.0000x reference)
//
#include <hip/hip_runtime.h>

// BinaryHungarianMatcherV2: C[b,q,t] = 5*L1(pred_box, tgt_box)
//                                    + 2*focal_class(logit[b,q])
//                                    + 2*(-giou(pred_box, tgt_box)),
// masked to 1e9 where t >= num_boxes[b].
// B=32, Q=1800, T=500. Output 115.2 MB fp32 -> store-BW bound (~18us floor).

#define K_COST_CLASS 2.0f
#define K_COST_BBOX  5.0f
#define K_COST_GIOU  2.0f
#define K_ALPHA      0.25f
#define K_INVALID    1.0e9f

constexpr int B = 32;
constexpr int Q = 1800;
constexpr int T = 500;

__global__ __launch_bounds__(128) void matcher_cost_kernel(
    const float* __restrict__ pred_logits,   // [B,Q,1]
    const float* __restrict__ pred_boxes,    // [B,Q,4] cxcywh
    const float* __restrict__ boxes_padded,  // [B,T,4] cxcywh
    const int*   __restrict__ num_boxes,     // [B]
    float* __restrict__ out)                 // [B,Q,T]
{
    const int bq  = blockIdx.x;            // b*Q + q
    const int b   = bq / Q;
    const int tid = threadIdx.x;

    // ---- per-(b,q) values (uniform across block; cheap redundant compute) ----
    const float4 pb = *reinterpret_cast<const float4*>(pred_boxes + (size_t)bq * 4);
    const float pcx = pb.x, pcy = pb.y, pw = pb.z, ph = pb.w;
    const float px0 = pcx - 0.5f * pw, py0 = pcy - 0.5f * ph;
    const float px1 = pcx + 0.5f * pw, py1 = pcy + 0.5f * ph;
    const float parea = pw * ph;

    const float s = pred_logits[bq];
    // stable log-sigmoid: log_sigmoid(x) = min(x,0) - log1p(exp(-|x|))
    const float lse      = log1pf(__expf(-fabsf(s)));
    const float log_p    = fminf(s, 0.f) - lse;    // log sigmoid(s)
    const float log_1mp  = fminf(-s, 0.f) - lse;   // log sigmoid(-s)
    const float p        = 1.f / (1.f + __expf(-s));
    const float omp      = 1.f - p;
    const float cls_cost = -K_ALPHA * omp * omp * log_p
                         + (1.f - K_ALPHA) * p * p * log_1mp;
    const float cls_term = K_COST_CLASS * cls_cost;

    const int nb = num_boxes[b];

    const int t0 = tid * 4;
    if (t0 >= T) return;   // 125 active threads cover T=500

    const float4* tb_base =
        reinterpret_cast<const float4*>(boxes_padded + ((size_t)b * T + t0) * 4);

    float4 res;
    float* resp = &res.x;
#pragma unroll
    for (int j = 0; j < 4; ++j) {
        const int t = t0 + j;
        const float4 tb = tb_base[j];   // 64B/thread, coalesced; L1/L2 resident
        const float tcx = tb.x, tcy = tb.y, tw = tb.z, th = tb.w;

        // L1 distance in cxcywh space
        const float cb = fabsf(pcx - tcx) + fabsf(pcy - tcy)
                       + fabsf(pw - tw)  + fabsf(ph - th);

        // GIoU in xyxy space
        const float tx0 = tcx - 0.5f * tw, ty0 = tcy - 0.5f * th;
        const float tx1 = tcx + 0.5f * tw, ty1 = tcy + 0.5f * th;
        const float tarea = tw * th;

        const float iw = fmaxf(fminf(px1, tx1) - fmaxf(px0, tx0), 0.f);
        const float ih = fmaxf(fminf(py1, ty1) - fmaxf(py0, ty0), 0.f);
        const float inter = iw * ih;
        const float uni   = parea + tarea - inter;
        const float iou   = inter / uni;

        const float ew = fmaxf(fmaxf(px1, tx1) - fminf(px0, tx0), 0.f);
        const float eh = fmaxf(fmaxf(py1, ty1) - fminf(py0, ty0), 0.f);
        const float earea = ew * eh;
        const float giou  = iou - (earea - uni) / earea;

        const float c = K_COST_BBOX * cb + cls_term - K_COST_GIOU * giou;
        resp[j] = (t < nb) ? c : K_INVALID;
    }

    // row start (b*Q+q)*T*4 bytes = bq*2000 B -> 16B aligned; t0 multiple of 4
    reinterpret_cast<float4*>(out + (size_t)bq * T)[tid] = res;
}

extern "C" void kernel_launch(void* const* d_in, const int* in_sizes, int n_in,
                              void* d_out, int out_size, void* d_ws, size_t ws_size,
                              hipStream_t stream) {
    const float* pred_logits  = (const float*)d_in[0];
    const float* pred_boxes   = (const float*)d_in[1];
    const float* boxes_padded = (const float*)d_in[2];
    const int*   num_boxes    = (const int*)d_in[3];
    float* out = (float*)d_out;

    dim3 grid(B * Q);
    dim3 block(128);
    matcher_cost_kernel<<<grid, block, 0, stream>>>(
        pred_logits, pred_boxes, boxes_padded, num_boxes, out);
}

// Round 2
// 150.726 us; speedup vs baseline: 1.1620x; 1.1620x over previous
//
#include <hip/hip_runtime.h>

// BinaryHungarianMatcherV2 cost matrix. B=32,Q=1800,T=500, out 115.2MB fp32.
// R1: VALU-bound (94% busy) from IEEE div sequences + log1pf libm call.
// R2: v_rcp_f32 for all divisions, __logf/__expf setup, drop redundant clamps.

#define K_COST_CLASS 2.0f
#define K_COST_BBOX  5.0f
#define K_COST_GIOU  2.0f
#define K_ALPHA      0.25f
#define K_INVALID    1.0e9f

constexpr int B = 32;
constexpr int Q = 1800;
constexpr int T = 500;

__global__ __launch_bounds__(128) void matcher_cost_kernel(
    const float* __restrict__ pred_logits,   // [B,Q,1]
    const float* __restrict__ pred_boxes,    // [B,Q,4] cxcywh
    const float* __restrict__ boxes_padded,  // [B,T,4] cxcywh
    const int*   __restrict__ num_boxes,     // [B]
    float* __restrict__ out)                 // [B,Q,T]
{
    const int bq  = blockIdx.x;            // b*Q + q
    const int b   = bq / Q;
    const int tid = threadIdx.x;

    const int t0 = tid * 4;
    if (t0 >= T) return;   // 125 of 128 threads active

    // ---- per-(b,q) setup (block-uniform; cheap fast-math version) ----
    const float4 pb = *reinterpret_cast<const float4*>(pred_boxes + (size_t)bq * 4);
    const float pcx = pb.x, pcy = pb.y, pw = pb.z, ph = pb.w;
    const float px0 = __builtin_fmaf(-0.5f, pw, pcx);
    const float py0 = __builtin_fmaf(-0.5f, ph, pcy);
    const float px1 = __builtin_fmaf( 0.5f, pw, pcx);
    const float py1 = __builtin_fmaf( 0.5f, ph, pcy);
    const float parea = pw * ph;

    const float s = pred_logits[bq];
    // one exp serves sigmoid + both log-sigmoids:
    //   e = exp(-|s|);  lse = log(1+e)
    //   log_sigmoid(s)  = min(s,0)  - lse
    //   log_sigmoid(-s) = min(-s,0) - lse
    //   sigmoid(s) = (s>=0) ? 1/(1+e) : e/(1+e)
    const float e_na = __expf(-fabsf(s));                       // v_exp
    const float lse  = __logf(1.f + e_na);                      // v_log * ln2
    const float log_p   = fminf(s, 0.f) - lse;
    const float log_1mp = fminf(-s, 0.f) - lse;
    const float r1pe = __builtin_amdgcn_rcpf(1.f + e_na);       // v_rcp
    const float p    = (s >= 0.f) ? r1pe : e_na * r1pe;
    const float omp  = 1.f - p;
    const float cls_term = K_COST_CLASS *
        (-K_ALPHA * omp * omp * log_p + (1.f - K_ALPHA) * p * p * log_1mp);

    const int nb = num_boxes[b];

    const float4* tb_base =
        reinterpret_cast<const float4*>(boxes_padded + ((size_t)b * T + t0) * 4);

    float r[4];
#pragma unroll
    for (int j = 0; j < 4; ++j) {
        const int t = t0 + j;
        const float4 tb = tb_base[j];   // coalesced 16B; L1/L2 resident
        const float tcx = tb.x, tcy = tb.y, tw = tb.z, th = tb.w;

        // L1 distance in cxcywh space (abs folds into add as input modifier)
        const float cb = fabsf(pcx - tcx) + fabsf(pcy - tcy)
                       + fabsf(pw - tw)  + fabsf(ph - th);

        // target xyxy (fma each)
        const float tx0 = __builtin_fmaf(-0.5f, tw, tcx);
        const float ty0 = __builtin_fmaf(-0.5f, th, tcy);
        const float tx1 = __builtin_fmaf( 0.5f, tw, tcx);
        const float ty1 = __builtin_fmaf( 0.5f, th, tcy);
        const float tarea = tw * th;

        // intersection (clamped), union, iou via rcp
        const float iw = fmaxf(fminf(px1, tx1) - fmaxf(px0, tx0), 0.f);
        const float ih = fmaxf(fminf(py1, ty1) - fmaxf(py0, ty0), 0.f);
        const float inter = iw * ih;
        const float uni   = parea + tarea - inter;
        const float iou   = inter * __builtin_amdgcn_rcpf(uni);

        // enclosing box: max-min >= 0 always, no clamp needed
        const float ew = fmaxf(px1, tx1) - fminf(px0, tx0);
        const float eh = fmaxf(py1, ty1) - fminf(py0, ty0);
        const float earea = ew * eh;
        const float giou  = iou - (earea - uni) * __builtin_amdgcn_rcpf(earea);

        // C = 5*cb + cls_term - 2*giou
        const float c = __builtin_fmaf(K_COST_BBOX, cb,
                        __builtin_fmaf(-K_COST_GIOU, giou, cls_term));
        r[j] = (t < nb) ? c : K_INVALID;
    }

    float4 res = make_float4(r[0], r[1], r[2], r[3]);
    reinterpret_cast<float4*>(out + (size_t)bq * T)[tid] = res;
}

extern "C" void kernel_launch(void* const* d_in, const int* in_sizes, int n_in,
                              void* d_out, int out_size, void* d_ws, size_t ws_size,
                              hipStream_t stream) {
    const float* pred_logits  = (const float*)d_in[0];
    const float* pred_boxes   = (const float*)d_in[1];
    const float* boxes_padded = (const float*)d_in[2];
    const int*   num_boxes    = (const int*)d_in[3];
    float* out = (float*)d_out;

    dim3 grid(B * Q);
    dim3 block(128);
    matcher_cost_kernel<<<grid, block, 0, stream>>>(
        pred_logits, pred_boxes, boxes_padded, num_boxes, out);
}

// Round 3
// 144.256 us; speedup vs baseline: 1.2141x; 1.0448x over previous
//
#include <hip/hip_runtime.h>

// BinaryHungarianMatcherV2 cost matrix. B=32,Q=1800,T=500, out 115.2MB fp32.
// R1: one block per (b,q), 83us, VALU-bound 94%.
// R2: rcp + fast transcendentals, ~59us (kernel), still VALU/overhead-bound.
// R3: restructure — precompute pred-side (transcendentals) once per (b,q) into
//     ws; main kernel: thread owns 4 t's (target regs hoisted), loops over q
//     reading pred values as wave-uniform s_loads; single-rcp fused giou.

#define K_COST_CLASS 2.0f
#define K_COST_BBOX  5.0f
#define K_COST_GIOU  2.0f
#define K_ALPHA      0.25f
#define K_INVALID    1.0e9f

constexpr int B = 32;
constexpr int Q = 1800;
constexpr int T = 500;
constexpr int QCHUNK = 25;        // q's per block iteration; grid.x = 72
constexpr int PSTRIDE = 16;       // floats per (b,q) in ws (64B aligned)

// ---------------- pass 1: per-(b,q) pred-derived values -> ws ----------------
__global__ __launch_bounds__(256) void precompute_pred(
    const float* __restrict__ pred_logits,   // [B,Q,1]
    const float* __restrict__ pred_boxes,    // [B,Q,4]
    float* __restrict__ P)                   // [B*Q,16]
{
    const int i = blockIdx.x * 256 + threadIdx.x;   // bq
    if (i >= B * Q) return;

    const float4 pb = *reinterpret_cast<const float4*>(pred_boxes + (size_t)i * 4);
    const float pcx = pb.x, pcy = pb.y, pw = pb.z, ph = pb.w;
    const float px0 = __builtin_fmaf(-0.5f, pw, pcx);
    const float py0 = __builtin_fmaf(-0.5f, ph, pcy);
    const float px1 = __builtin_fmaf( 0.5f, pw, pcx);
    const float py1 = __builtin_fmaf( 0.5f, ph, pcy);
    const float parea = pw * ph;

    const float s = pred_logits[i];
    const float e_na = __expf(-fabsf(s));
    const float lse  = __logf(1.f + e_na);
    const float log_p   = fminf(s, 0.f) - lse;
    const float log_1mp = fminf(-s, 0.f) - lse;
    const float r1pe = __builtin_amdgcn_rcpf(1.f + e_na);
    const float p    = (s >= 0.f) ? r1pe : e_na * r1pe;
    const float omp  = 1.f - p;
    const float cls_term = K_COST_CLASS *
        (-K_ALPHA * omp * omp * log_p + (1.f - K_ALPHA) * p * p * log_1mp);

    float4* o = reinterpret_cast<float4*>(P + (size_t)i * PSTRIDE);
    o[0] = make_float4(px0, py0, px1, py1);
    o[1] = make_float4(pcx, pcy, pw, ph);
    o[2] = make_float4(parea, cls_term, 0.f, 0.f);
}

// ---------------- pass 2: main cost kernel ----------------
__global__ __launch_bounds__(128) void matcher_cost_kernel(
    const float* __restrict__ boxes_padded,  // [B,T,4] cxcywh
    const int*   __restrict__ num_boxes,     // [B]
    const float* __restrict__ P,             // [B*Q,16] pred-derived
    float* __restrict__ out)                 // [B,Q,T]
{
    const int b  = blockIdx.y;
    const int q0 = blockIdx.x * QCHUNK;
    const int tid = threadIdx.x;
    const int t0  = tid * 4;
    if (t0 >= T) return;    // 125/128 active

    const int nb = num_boxes[b];

    // ---- hoist 4 target boxes into registers (once per QCHUNK q's) ----
    const float4* tb_base =
        reinterpret_cast<const float4*>(boxes_padded + ((size_t)b * T + t0) * 4);
    float tcx[4], tcy[4], tw_[4], th_[4];
    float tx0[4], ty0[4], tx1[4], ty1[4], tarea[4];
    bool  valid[4];
#pragma unroll
    for (int j = 0; j < 4; ++j) {
        const float4 tb = tb_base[j];
        tcx[j] = tb.x; tcy[j] = tb.y; tw_[j] = tb.z; th_[j] = tb.w;
        tx0[j] = __builtin_fmaf(-0.5f, tb.z, tb.x);
        ty0[j] = __builtin_fmaf(-0.5f, tb.w, tb.y);
        tx1[j] = __builtin_fmaf( 0.5f, tb.z, tb.x);
        ty1[j] = __builtin_fmaf( 0.5f, tb.w, tb.y);
        tarea[j] = tb.z * tb.w;
        valid[j] = (t0 + j) < nb;
    }

    float4* orow0 = reinterpret_cast<float4*>(out + ((size_t)b * Q + q0) * T);

#pragma unroll 2
    for (int qi = 0; qi < QCHUNK; ++qi) {
        // wave-uniform address -> scalar loads (no VALU cost)
        const float* p = P + ((size_t)b * Q + (q0 + qi)) * PSTRIDE;
        const float px0 = p[0], py0 = p[1], px1 = p[2], py1 = p[3];
        const float pcx = p[4], pcy = p[5], pw = p[6], ph = p[7];
        const float parea = p[8], cls_term = p[9];

        float r[4];
#pragma unroll
        for (int j = 0; j < 4; ++j) {
            // L1 cost in cxcywh
            const float cb = fabsf(pcx - tcx[j]) + fabsf(pcy - tcy[j])
                           + fabsf(pw - tw_[j]) + fabsf(ph - th_[j]);

            const float iw = fmaxf(fminf(px1, tx1[j]) - fmaxf(px0, tx0[j]), 0.f);
            const float ih = fmaxf(fminf(py1, ty1[j]) - fmaxf(py0, ty0[j]), 0.f);
            const float inter = iw * ih;
            const float uni   = (parea + tarea[j]) - inter;

            const float ew = fmaxf(px1, tx1[j]) - fminf(px0, tx0[j]);
            const float eh = fmaxf(py1, ty1[j]) - fminf(py0, ty0[j]);
            const float earea = ew * eh;

            // fused giou: (earea*(inter-uni) + uni^2) / (uni*earea)  -- one rcp
            const float num    = __builtin_fmaf(earea, inter - uni, uni * uni);
            const float rdenom = __builtin_amdgcn_rcpf(uni * earea);
            const float giou   = num * rdenom;

            const float c = __builtin_fmaf(K_COST_BBOX, cb,
                            __builtin_fmaf(-K_COST_GIOU, giou, cls_term));
            r[j] = valid[j] ? c : K_INVALID;
        }
        orow0[(size_t)qi * (T / 4) + tid] = make_float4(r[0], r[1], r[2], r[3]);
    }
}

extern "C" void kernel_launch(void* const* d_in, const int* in_sizes, int n_in,
                              void* d_out, int out_size, void* d_ws, size_t ws_size,
                              hipStream_t stream) {
    const float* pred_logits  = (const float*)d_in[0];
    const float* pred_boxes   = (const float*)d_in[1];
    const float* boxes_padded = (const float*)d_in[2];
    const int*   num_boxes    = (const int*)d_in[3];
    float* out = (float*)d_out;
    float* P   = (float*)d_ws;   // B*Q*16 floats = 921.6 KB

    precompute_pred<<<dim3((B * Q + 255) / 256), dim3(256), 0, stream>>>(
        pred_logits, pred_boxes, P);

    dim3 grid(Q / QCHUNK, B);    // 72 x 32 = 2304 blocks
    matcher_cost_kernel<<<grid, dim3(128), 0, stream>>>(
        boxes_padded, num_boxes, P, out);
}